// Round 15
// baseline (84.612 us; speedup 1.0000x reference)
//
#include <hip/hip_runtime.h>

#define NBATCH 8192
#define DD 512
#define NIDS 1000000
#define BCNT 4096
#define NCT 5
#define INV_TEMP 14.285714285714286f
#define EPSF 1.1920929e-07f
#define FPSCALE 16.0f
#define INV_SIMSCALE (1.0f / 256.0f)

typedef __attribute__((ext_vector_type(4))) float f32x4;
typedef __attribute__((ext_vector_type(2))) long lx2;

// ---------------- workspace layout (bytes) ----------------
#define OFF_LP     ((size_t)0)            // 256 floats: 32 blk x 4 wave x (lI,lT)
#define OFF_CE1    ((size_t)1024)         // 320 floats: CE sum partials
#define OFF_CE2    ((size_t)2304)         // 320 floats: count partials
#define OFF_CE3    ((size_t)3584)         // 320 floats: last-loss partials
#define OFF_POS    ((size_t)(32*1024))
#define OFF_RNK    ((size_t)(64*1024))
#define OFF_CNT    ((size_t)(96*1024))
#define OFF_DA     ((size_t)(100*1024))
#define OFF_RA0    ((size_t)(132*1024))
#define OFF_RB0    ((size_t)(164*1024))
#define OFF_RA1    ((size_t)(196*1024))
#define OFF_RB1    ((size_t)(228*1024))
#define OFF_SIV    ((size_t)(260*1024))
#define OFF_STV    ((size_t)(292*1024))
#define OFF_WINI   ((size_t)(324*1024))
#define OFF_WINT   (OFF_WINI + 4000000)
#define OFF_MA     (OFF_WINT + 4000000)
#define MATB       ((size_t)(8192*512*2))
#define OFF_MB     (OFF_MA + MATB)
#define OFF_MC     (OFF_MB + MATB)
#define OFF_MD     (OFF_MC + MATB)

// fp8 blocked-swizzled operand layout (r13-verified):
// panel = row/128 (stride 65536 B), K64-tile kc = k/64 (stride 8192 B),
// within-tile row-major [128][64B]; each 64B row = 4 granules of 16B;
// granule c holds k-bytes [8c..8c+7] ++ [32+8c..32+8c+7]; granule base byte
// XOR-swizzled by ((row&6)<<3) — verified-0-conflict algebra.

// K1: single-block compaction (1024 thr x 8 items) + rA/rB zero (1024 x 8).
__global__ void k_compact(const int* __restrict__ slabel, int* __restrict__ pos,
                          int* __restrict__ rnk, int* __restrict__ cnts,
                          float* __restrict__ rA0, float* __restrict__ rB0,
                          float* __restrict__ rA1, float* __restrict__ rB1) {
    __shared__ int sums[1024];
    int tid = threadIdx.x;
#pragma unroll
    for (int j = 0; j < 8; ++j) {
        int v = tid * 8 + j;
        rA0[v] = 0.f; rB0[v] = 0.f; rA1[v] = 0.f; rB1[v] = 0.f;
    }
    int flags[8];
    int c = 0;
    int base = tid * 8;
#pragma unroll
    for (int j = 0; j < 8; ++j) { flags[j] = (slabel[base + j] == 1); c += flags[j]; }
    sums[tid] = c;
    __syncthreads();
    for (int off = 1; off < 1024; off <<= 1) {
        int add = (tid >= off) ? sums[tid - off] : 0;
        __syncthreads();
        sums[tid] += add;
        __syncthreads();
    }
    int p = sums[tid] - c;  // exclusive prefix of pos count
#pragma unroll
    for (int j = 0; j < 8; ++j) {
        int idx = base + j;
        if (flags[j]) { pos[p] = idx; rnk[idx] = p; p++; }
        else rnk[idx] = idx - p;
    }
    if (tid == 0) { cnts[0] = sums[1023]; cnts[1] = NBATCH - sums[1023]; }
}

// K2: fused gather (bid 0..2047) + CE (bid 2048..2111); ALL 2112 blocks carry
// a strided slice of the s_I/s_T -> out copy (2 reps x 540672 >= 1M) so the
// heavy init launch disappears. Gather: read img[i],txt[i] once (f32), diag
// dot f32, fp8-e4m3 convert (scale 16), route to (mA,mC)/(mD,mB) in the
// blocked-swizzled layout; targeted winner init.
__global__ __launch_bounds__(256) void k_gather(
        const float* __restrict__ img, const float* __restrict__ txt,
        const int* __restrict__ slabel, const int* __restrict__ rnk,
        const int* __restrict__ image_ids, const int* __restrict__ text_ids,
        int* __restrict__ winI, int* __restrict__ winT,
        unsigned char* __restrict__ mA, unsigned char* __restrict__ mB,
        unsigned char* __restrict__ mC, unsigned char* __restrict__ mD,
        float* __restrict__ dA,
        const float* __restrict__ sI, const float* __restrict__ sT,
        float* __restrict__ out,
        const float* __restrict__ imgc, const float* __restrict__ tfc,
        const int* __restrict__ labels, const float* __restrict__ lastl,
        float* __restrict__ ce1, float* __restrict__ ce2, float* __restrict__ ce3) {
    int bid = blockIdx.x;
    int tid = threadIdx.x;
    // ---- init slice: s_I/s_T copy into out (all blocks) ----
#pragma unroll
    for (int rep = 0; rep < 2; ++rep) {
        int iv = rep * 540672 + bid * 256 + tid;
        if (iv < NIDS) {
            out[1 + iv] = sI[iv];
            out[1 + NIDS + iv] = sT[iv];
        }
    }

    if (bid < 2048) {
        int kk = bid * 256 + tid;
        if (kk < NBATCH) {
            winI[image_ids[kk]] = -1;
            winT[text_ids[kk]] = -1;
        }
        int i = bid * 4 + (tid >> 6);         // one wave per batch row
        int g = tid & 63;                      // 8-element chunk, k = 8g..8g+7
        const float4* ip = (const float4*)(img + (size_t)i * DD) + g * 2;
        const float4* tp = (const float4*)(txt + (size_t)i * DD) + g * 2;
        float4 v0 = ip[0], v1 = ip[1], t0 = tp[0], t1 = tp[1];
        float part = v0.x * t0.x + v0.y * t0.y + v0.z * t0.z + v0.w * t0.w
                   + v1.x * t1.x + v1.y * t1.y + v1.z * t1.z + v1.w * t1.w;
        for (int off = 32; off; off >>= 1) part += __shfl_xor(part, off);

        int lab = (slabel[i] == 1);
        int r = rnk[i];

        int ilo = __builtin_amdgcn_cvt_pk_fp8_f32(v0.x * FPSCALE, v0.y * FPSCALE, 0, 0);
        ilo = __builtin_amdgcn_cvt_pk_fp8_f32(v0.z * FPSCALE, v0.w * FPSCALE, ilo, 1);
        int ihi = __builtin_amdgcn_cvt_pk_fp8_f32(v1.x * FPSCALE, v1.y * FPSCALE, 0, 0);
        ihi = __builtin_amdgcn_cvt_pk_fp8_f32(v1.z * FPSCALE, v1.w * FPSCALE, ihi, 1);
        int tlo = __builtin_amdgcn_cvt_pk_fp8_f32(t0.x * FPSCALE, t0.y * FPSCALE, 0, 0);
        tlo = __builtin_amdgcn_cvt_pk_fp8_f32(t0.z * FPSCALE, t0.w * FPSCALE, tlo, 1);
        int thi = __builtin_amdgcn_cvt_pk_fp8_f32(t1.x * FPSCALE, t1.y * FPSCALE, 0, 0);
        thi = __builtin_amdgcn_cvt_pk_fp8_f32(t1.z * FPSCALE, t1.w * FPSCALE, thi, 1);

        int rl = r & 127;
        int cp = g & 7;                        // chunk within K64 tile
        int gran = cp & 3, half = cp >> 2;
        int swb = ((gran * 16) ^ ((rl & 6) << 3)) + half * 8;
        size_t off = (size_t)(r >> 7) * 65536 + (size_t)(g >> 3) * 8192 + rl * 64 + swb;
        unsigned char* dI = lab ? mA : mD;     // img -> A (pos) or D (neg)
        unsigned char* dT = lab ? mC : mB;     // txt -> C (pos) or B (neg)
        *(int2*)(dI + off) = make_int2(ilo, ihi);
        *(int2*)(dT + off) = make_int2(tlo, thi);
        if (lab && g == 0) dA[r] = part;
    } else {
        // ---- CE block cb in [0,64): 4 rows/iter x 16 iters; partial outputs ----
        int cb = bid - 2048;
        __shared__ float tS[NCT * DD];
        __shared__ float sce[NCT], scn[NCT], sls[NCT];
        for (int j = tid; j < NCT * DD; j += 256) tS[j] = tfc[j];
        if (tid < NCT) { sce[tid] = 0.f; scn[tid] = 0.f; sls[tid] = 0.f; }
        __syncthreads();
        int lane = tid & 63;
        int wid = tid >> 6;
        for (int it = 0; it < 16; ++it) {
            int r = it * 256 + cb * 4 + wid;
            const float4* ip = (const float4*)(imgc + (size_t)r * DD) + lane * 2;
            float4 a0 = ip[0], a1 = ip[1];
            float p[NCT];
#pragma unroll
            for (int c = 0; c < NCT; ++c) {
                const float* t = &tS[c * DD + lane * 8];
                p[c] = a0.x * t[0] + a0.y * t[1] + a0.z * t[2] + a0.w * t[3]
                     + a1.x * t[4] + a1.y * t[5] + a1.z * t[6] + a1.w * t[7];
            }
#pragma unroll
            for (int c = 0; c < NCT; ++c)
                for (int off = 32; off; off >>= 1) p[c] += __shfl_xor(p[c], off);
            if (lane == 0) {
                float l[NCT];
                float mx = -1e30f;
#pragma unroll
                for (int c = 0; c < NCT; ++c) { l[c] = p[c] * 10.0f; mx = fmaxf(mx, l[c]); }
                float ssum = 0.f;
#pragma unroll
                for (int c = 0; c < NCT; ++c) ssum += __expf(l[c] - mx);
                float lse = mx + __logf(ssum);
                int lb = labels[r];
                float ce = lse - l[lb];
                atomicAdd(&sce[lb], ce);
                atomicAdd(&scn[lb], 1.f);
                atomicAdd(&sls[lb], lastl[r]);
            }
        }
        __syncthreads();
        if (tid < NCT) {
            ce1[cb * 5 + tid] = sce[tid];
            ce2[cb * 5 + tid] = scn[tid];
            ce3[cb * 5 + tid] = sls[tid];
        }
    }
}

__device__ __forceinline__ void gl16(const void* src, void* lds) {
    __builtin_amdgcn_global_load_lds((const __attribute__((address_space(1))) void*)src,
                                     (__attribute__((address_space(3))) void*)lds, 16, 0, 0);
}

#define VM4()  asm volatile("s_waitcnt vmcnt(4)" ::: "memory")
#define VM0()  asm volatile("s_waitcnt vmcnt(0)" ::: "memory")
#define BARR() asm volatile("s_barrier" ::: "memory")

// K3: 128x128x(K=512) fp8-e4m3 MFMA GEMM — BYTE-IDENTICAL to rounds 13/14
// (the control): 4 waves 2x2, BK=64 fp8, 2-buf, VM4 counted-vmcnt publish-
// barrier pipeline, 0-conflict swizzled ds_read_b128, 36KB LDS-staged
// epilogue. Measured at ~99% of the 128 B/cyc LDS-pipe floor (r13).
__global__ __launch_bounds__(256) void k_gemm(
        const unsigned char* __restrict__ mA, const unsigned char* __restrict__ mB,
        const unsigned char* __restrict__ mC, const unsigned char* __restrict__ mD,
        const float* __restrict__ dA, const int* __restrict__ cnts,
        float* __restrict__ rA0, float* __restrict__ rB0,
        float* __restrict__ rA1, float* __restrict__ rB1) {
    int P = cnts[0], Nn = cnts[1];
    int bm = blockIdx.x * 128, bn = blockIdx.y * 128;
    if (bm >= P || bn >= Nn) return;
    int z = blockIdx.z;
    const unsigned char* Ap = (z ? mC : mA) + (size_t)blockIdx.x * 65536;
    const unsigned char* Bp = (z ? mD : mB) + (size_t)blockIdx.y * 65536;
    float* rA = z ? rA1 : rA0;
    float* rB = z ? rB1 : rB0;

    __shared__ __align__(16) char SRAW[36864];   // 32KB staging / 36KB epilogue
    char* S = SRAW;                              // buf p: A at p*16384, B at +8192

    int tid = threadIdx.x;
    int lane = tid & 63;
    int wid = tid >> 6;
    int wr = wid >> 1, wc = wid & 1;          // wave tile 64x64
    int bo = tid * 16;                         // staging byte offset (linear)

    int kswz = ((lane >> 4) * 16) ^ ((lane & 6) << 3);
    int abyte = (wr * 64 + (lane & 15)) * 64 + kswz;   // A frag m: +m*1024
    int bbyte = (wc * 64 + (lane & 15)) * 64 + kswz;   // B frag n: +n*1024

    f32x4 acc[4][4];
#pragma unroll
    for (int m = 0; m < 4; ++m)
#pragma unroll
        for (int n = 0; n < 4; ++n) acc[m][n] = (f32x4){0.f, 0.f, 0.f, 0.f};

#define STAGE(kt, p) do { \
        gl16(Ap + (kt) * 8192 + bo,        S + (p) * 16384 + bo); \
        gl16(Ap + (kt) * 8192 + bo + 4096, S + (p) * 16384 + bo + 4096); \
        gl16(Bp + (kt) * 8192 + bo,        S + (p) * 16384 + 8192 + bo); \
        gl16(Bp + (kt) * 8192 + bo + 4096, S + (p) * 16384 + 8192 + bo + 4096); } while (0)

    STAGE(0, 0);
    STAGE(1, 1);
    VM4();                 // own tile-0 loads landed (tile-1's 4 still in flight)
    BARR();                // publish tile 0

#pragma unroll
    for (int kt = 0; kt < 8; ++kt) {
        const int cur = kt & 1;
        const char* base = S + cur * 16384;
        lx2 af[4], bf[4];
#pragma unroll
        for (int m = 0; m < 4; ++m)
            af[m] = *(const lx2*)(base + abyte + m * 1024);
#pragma unroll
        for (int n = 0; n < 4; ++n)
            bf[n] = *(const lx2*)(base + 8192 + bbyte + n * 1024);
#pragma unroll
        for (int m = 0; m < 4; ++m)
#pragma unroll
            for (int n = 0; n < 4; ++n)
                acc[m][n] = __builtin_amdgcn_mfma_f32_16x16x32_fp8_fp8(af[m][0], bf[n][0], acc[m][n], 0, 0, 0);
#pragma unroll
        for (int m = 0; m < 4; ++m)
#pragma unroll
            for (int n = 0; n < 4; ++n)
                acc[m][n] = __builtin_amdgcn_mfma_f32_16x16x32_fp8_fp8(af[m][1], bf[n][1], acc[m][n], 0, 0, 0);
        if (kt < 7) {
            BARR();                            // all waves consumed S[cur]
            if (kt + 2 < 8) {
                STAGE(kt + 2, cur);            // refill cur with tile kt+2
                VM4();                         // tile kt+1 landed (own loads)
            } else {
                VM0();                         // tail
            }
            BARR();                            // publish tile kt+1
        }
    }
#undef STAGE

    // ---- epilogue: e = exp((s-diag)/T); row-sums of e and e*df via LDS ----
    BARR();                                    // all waves done with staging LDS
    float* F = (float*)SRAW;                   // row R = wc*128+wr*64+wrow, stride 36, 16x(pa,pb)
    int col = lane & 15;
    int rsub = (lane >> 4) * 4;
    int rowbase = bm + wr * 64;
    int colb = bn + wc * 64 + col;
    int fb = ((wc << 7) + (wr << 6)) * 36 + col * 2;
#pragma unroll
    for (int m = 0; m < 4; ++m) {
#pragma unroll
        for (int r = 0; r < 4; ++r) {
            int wrow = m * 16 + rsub + r;
            float dv = dA[rowbase + wrow];
            float pa = 0.f, pb = 0.f;
#pragma unroll
            for (int n = 0; n < 4; ++n) {
                int gcol = colb + n * 16;
                float sv = acc[m][n][r] * INV_SIMSCALE;
                float df = sv - dv;
                float e = (gcol < Nn) ? __expf(df * INV_TEMP) : 0.f;
                pa += e;
                pb += e * df;
            }
            *(float2*)&F[fb + wrow * 36] = make_float2(pa, pb);
        }
    }
    BARR();
    {
        int row = tid >> 1;
        int half = tid & 1;
        const float4* Fr = (const float4*)&F[((half << 7) + row) * 36];
        float sa = 0.f, sb = 0.f;
#pragma unroll
        for (int q = 0; q < 8; ++q) {
            float4 v = Fr[q];
            sa += v.x + v.z;
            sb += v.y + v.w;
        }
        sa += __shfl_xor(sa, 1);
        sb += __shfl_xor(sb, 1);
        int grow = bm + row;
        if (!half && grow < P) {
            atomicAdd(&rA[grow], sa);
            atomicAdd(&rB[grow], sb);
        }
    }
}

// K4: per-positive finalize: g, s-update, per-row losses (per-wave partial
// stores), winner atomicMax
__global__ void k_posfin(const int* __restrict__ cnts, const int* __restrict__ pos,
                         const float* __restrict__ rA0, const float* __restrict__ rB0,
                         const float* __restrict__ rA1, const float* __restrict__ rB1,
                         const int* __restrict__ image_ids, const int* __restrict__ text_ids,
                         const float* __restrict__ sIin, const float* __restrict__ sTin,
                         const int* __restrict__ epochp,
                         float* __restrict__ sIv, float* __restrict__ sTv,
                         int* __restrict__ winI, int* __restrict__ winT,
                         float* __restrict__ lp) {
    int k = blockIdx.x * 256 + threadIdx.x;
    int P = cnts[0], Nn = cnts[1];
    float invNn = 1.f / (float)Nn;
    int epoch = epochp[0];
    float lI = 0.f, lT = 0.f;
    if (k < P) {
        int i = pos[k];
        int idI = image_ids[i], idT = text_ids[i];
        float gI = rA0[k] * invNn;
        float sIvk = (epoch == 0) ? gI : 0.2f * sIin[idI] + 0.8f * gI;
        lI = (rB0[k] * invNn) / (sIvk + EPSF);
        float gT = rA1[k] * invNn;
        float sTvk = (epoch == 0) ? gT : 0.2f * sTin[idT] + 0.8f * gT;
        lT = (rB1[k] * invNn) / (sTvk + EPSF);
        sIv[k] = sIvk;
        sTv[k] = sTvk;
        atomicMax(&winI[idI], k);
        atomicMax(&winT[idT], k);
    }
    for (int off = 32; off; off >>= 1) { lI += __shfl_xor(lI, off); lT += __shfl_xor(lT, off); }
    if ((threadIdx.x & 63) == 0) {
        int slot = blockIdx.x * 4 + (threadIdx.x >> 6);
        lp[slot * 2] = lI;
        lp[slot * 2 + 1] = lT;
    }
}

// K5: scatter (last-occurrence-wins) + partial reductions + final scalars
__global__ void k_fin(const int* __restrict__ cnts, const int* __restrict__ pos,
                      const int* __restrict__ image_ids, const int* __restrict__ text_ids,
                      const int* __restrict__ winI, const int* __restrict__ winT,
                      const float* __restrict__ sIv, const float* __restrict__ sTv,
                      const float* __restrict__ lp, const float* __restrict__ ce1,
                      const float* __restrict__ ce2, const float* __restrict__ ce3,
                      const float* __restrict__ u, float* __restrict__ out) {
    int P = cnts[0];
    int k = blockIdx.x * 256 + threadIdx.x;
    if (k < P) {
        int i = pos[k];
        int a = image_ids[i];
        if (winI[a] == k) out[1 + a] = sIv[k];
        int b = text_ids[i];
        if (winT[b] == k) out[1 + NIDS + b] = sTv[k];
    }
    if (blockIdx.x == 0 && threadIdx.x < 64) {
        int lane = threadIdx.x;
        float lI = lp[2 * lane] + lp[2 * (lane + 64)];
        float lT = lp[2 * lane + 1] + lp[2 * (lane + 64) + 1];
        for (int off = 32; off; off >>= 1) { lI += __shfl_xor(lI, off); lT += __shfl_xor(lT, off); }
        float ce[NCT], cn[NCT], ls[NCT];
#pragma unroll
        for (int c = 0; c < NCT; ++c) {
            float a1 = ce1[lane * 5 + c], a2 = ce2[lane * 5 + c], a3 = ce3[lane * 5 + c];
            for (int off = 32; off; off >>= 1) {
                a1 += __shfl_xor(a1, off);
                a2 += __shfl_xor(a2, off);
                a3 += __shfl_xor(a3, off);
            }
            ce[c] = a1; cn[c] = a2; ls[c] = a3;
        }
        if (lane == 0) {
            float Pf = (float)P;
            float contrast = lI / Pf + lT / Pf;
            float u_sum = 0.f;
            float mc[NCT], cv[NCT], u_new[NCT];
            bool pres[NCT];
#pragma unroll
            for (int c = 0; c < NCT; ++c) {
                pres[c] = cn[c] > 0.f;
                float safe = fmaxf(cn[c], 1.f);
                mc[c] = ce[c] / safe;
                float ml = ls[c] / safe;
                cv[c] = mc[c] - ml;
                if (pres[c]) u_sum += u[c];
            }
            float np_ = 0.f, csum = 0.f;
#pragma unroll
            for (int c = 0; c < NCT; ++c) {
                float uu = (u_sum == 0.f) ? cv[c] : 0.2f * u[c] + 0.8f * cv[c];
                u_new[c] = pres[c] ? uu : u[c];
                if (pres[c]) {
                    np_ += 1.f;
                    csum += fmaxf(40.0f * u_new[c], 0.f) * mc[c] * 0.1f;
                }
                out[1 + 2 * NIDS + c] = u_new[c];
            }
            out[0] = contrast + csum / np_;
        }
    }
}

extern "C" void kernel_launch(void* const* d_in, const int* in_sizes, int n_in,
                              void* d_out, int out_size, void* d_ws, size_t ws_size,
                              hipStream_t stream) {
    const float* img = (const float*)d_in[0];
    const float* txt = (const float*)d_in[1];
    const int* image_ids = (const int*)d_in[2];
    const int* text_ids = (const int*)d_in[3];
    const int* slabel = (const int*)d_in[4];
    const int* epoch = (const int*)d_in[5];
    const float* imgc = (const float*)d_in[6];
    const float* tfc = (const float*)d_in[7];
    const int* labels = (const int*)d_in[8];
    const float* lastl = (const float*)d_in[9];
    const float* sI = (const float*)d_in[10];
    const float* sT = (const float*)d_in[11];
    const float* u = (const float*)d_in[12];
    float* out = (float*)d_out;
    char* ws = (char*)d_ws;

    float* lp = (float*)(ws + OFF_LP);
    float* ce1 = (float*)(ws + OFF_CE1);
    float* ce2 = (float*)(ws + OFF_CE2);
    float* ce3 = (float*)(ws + OFF_CE3);
    int* pos = (int*)(ws + OFF_POS);
    int* rnk = (int*)(ws + OFF_RNK);
    int* cnts = (int*)(ws + OFF_CNT);
    float* dA = (float*)(ws + OFF_DA);
    float* rA0 = (float*)(ws + OFF_RA0);
    float* rB0 = (float*)(ws + OFF_RB0);
    float* rA1 = (float*)(ws + OFF_RA1);
    float* rB1 = (float*)(ws + OFF_RB1);
    float* sIv = (float*)(ws + OFF_SIV);
    float* sTv = (float*)(ws + OFF_STV);
    int* winI = (int*)(ws + OFF_WINI);
    int* winT = (int*)(ws + OFF_WINT);
    unsigned char* mA = (unsigned char*)(ws + OFF_MA);
    unsigned char* mB = (unsigned char*)(ws + OFF_MB);
    unsigned char* mC = (unsigned char*)(ws + OFF_MC);
    unsigned char* mD = (unsigned char*)(ws + OFF_MD);

    k_compact<<<1, 1024, 0, stream>>>(slabel, pos, rnk, cnts, rA0, rB0, rA1, rB1);
    k_gather<<<2112, 256, 0, stream>>>(img, txt, slabel, rnk, image_ids, text_ids,
                                       winI, winT, mA, mB, mC, mD, dA,
                                       sI, sT, out, imgc, tfc, labels, lastl,
                                       ce1, ce2, ce3);
    k_gemm<<<dim3(64, 64, 2), 256, 0, stream>>>(mA, mB, mC, mD, dA, cnts, rA0, rB0, rA1, rB1);
    k_posfin<<<32, 256, 0, stream>>>(cnts, pos, rA0, rB0, rA1, rB1, image_ids, text_ids,
                                     sI, sT, epoch, sIv, sTv, winI, winT, lp);
    k_fin<<<32, 256, 0, stream>>>(cnts, pos, image_ids, text_ids, winI, winT,
                                  sIv, sTv, lp, ce1, ce2, ce3, u, out);
}

// Round 16
// 78.080 us; speedup vs baseline: 1.0837x; 1.0837x over previous
//
#include <hip/hip_runtime.h>

#define NBATCH 8192
#define DD 512
#define NIDS 1000000
#define BCNT 4096
#define NCT 5
#define INV_TEMP 14.285714285714286f
#define EPSF 1.1920929e-07f
#define FPSCALE 16.0f
#define INV_SIMSCALE (1.0f / 256.0f)

typedef __attribute__((ext_vector_type(4))) float f32x4;
typedef __attribute__((ext_vector_type(2))) long lx2;

// ---------------- workspace layout (bytes) ----------------
#define OFF_LP     ((size_t)0)            // 256 floats: 32 blk x 4 wave x (lI,lT)
#define OFF_CE1    ((size_t)1024)         // 320 floats: CE sum partials
#define OFF_CE2    ((size_t)2304)         // 320 floats: count partials
#define OFF_CE3    ((size_t)3584)         // 320 floats: last-loss partials
#define OFF_POS    ((size_t)(32*1024))
#define OFF_RNK    ((size_t)(64*1024))
#define OFF_CNT    ((size_t)(96*1024))
#define OFF_DA     ((size_t)(100*1024))
#define OFF_RA0    ((size_t)(132*1024))
#define OFF_RB0    ((size_t)(164*1024))
#define OFF_RA1    ((size_t)(196*1024))
#define OFF_RB1    ((size_t)(228*1024))
#define OFF_SIV    ((size_t)(260*1024))
#define OFF_STV    ((size_t)(292*1024))
#define OFF_WINI   ((size_t)(324*1024))
#define OFF_WINT   (OFF_WINI + 4000000)
#define OFF_MA     (OFF_WINT + 4000000)
#define MATB       ((size_t)(8192*512*2))
#define OFF_MB     (OFF_MA + MATB)
#define OFF_MC     (OFF_MB + MATB)
#define OFF_MD     (OFF_MC + MATB)

// fp8 blocked-swizzled operand layout (r13-verified):
// panel = row/128 (stride 65536 B), K64-tile kc = k/64 (stride 8192 B),
// within-tile row-major [128][64B]; each 64B row = 4 granules of 16B;
// granule c holds k-bytes [8c..8c+7] ++ [32+8c..32+8c+7]; granule base byte
// XOR-swizzled by ((row&6)<<3) — verified-0-conflict algebra.

// K1 (65 blocks): bid 0..63 = CE (per-block partial outputs); bid 64 =
// compaction; all blocks carry the rA/rB zero slice. The 8MB s-copy moved
// into k_gemm (its HBM is 94% idle) — so this launch is tiny.
__global__ __launch_bounds__(256) void k_pre(
        float* __restrict__ rA0, float* __restrict__ rB0,
        float* __restrict__ rA1, float* __restrict__ rB1,
        const int* __restrict__ slabel, int* __restrict__ pos,
        int* __restrict__ rnk, int* __restrict__ cnts,
        const float* __restrict__ imgc, const float* __restrict__ tfc,
        const int* __restrict__ labels, const float* __restrict__ lastl,
        float* __restrict__ ce1, float* __restrict__ ce2, float* __restrict__ ce3) {
    int bid = blockIdx.x;
    int tid = threadIdx.x;
    int iv = bid * 256 + tid;
    if (iv < NBATCH) { rA0[iv] = 0.f; rB0[iv] = 0.f; rA1[iv] = 0.f; rB1[iv] = 0.f; }

    if (bid == 64) {
        // ---- compaction: 256 threads x 32 items, stable scan ----
        __shared__ int sums[256];
        int base = tid * 32;
        int c = 0;
        for (int j = 0; j < 32; ++j) c += (slabel[base + j] == 1);
        sums[tid] = c;
        __syncthreads();
        for (int off = 1; off < 256; off <<= 1) {
            int add = (tid >= off) ? sums[tid - off] : 0;
            __syncthreads();
            sums[tid] += add;
            __syncthreads();
        }
        int p = sums[tid] - c;   // exclusive prefix of pos count
        for (int j = 0; j < 32; ++j) {
            int idx = base + j;
            if (slabel[idx] == 1) { pos[p] = idx; rnk[idx] = p; p++; }
            else rnk[idx] = idx - p;
        }
        if (tid == 255) { cnts[0] = sums[255]; cnts[1] = NBATCH - sums[255]; }
    } else {
        // ---- CE block cb in [0,64): 4 rows/iter x 16 iters; partial outputs ----
        int cb = bid;
        __shared__ float tS[NCT * DD];
        __shared__ float sce[NCT], scn[NCT], sls[NCT];
        for (int j = tid; j < NCT * DD; j += 256) tS[j] = tfc[j];
        if (tid < NCT) { sce[tid] = 0.f; scn[tid] = 0.f; sls[tid] = 0.f; }
        __syncthreads();
        int lane = tid & 63;
        int wid = tid >> 6;
        for (int it = 0; it < 16; ++it) {
            int r = it * 256 + cb * 4 + wid;
            const float4* ip = (const float4*)(imgc + (size_t)r * DD) + lane * 2;
            float4 a0 = ip[0], a1 = ip[1];
            float p[NCT];
#pragma unroll
            for (int c = 0; c < NCT; ++c) {
                const float* t = &tS[c * DD + lane * 8];
                p[c] = a0.x * t[0] + a0.y * t[1] + a0.z * t[2] + a0.w * t[3]
                     + a1.x * t[4] + a1.y * t[5] + a1.z * t[6] + a1.w * t[7];
            }
#pragma unroll
            for (int c = 0; c < NCT; ++c)
                for (int off = 32; off; off >>= 1) p[c] += __shfl_xor(p[c], off);
            if (lane == 0) {
                float l[NCT];
                float mx = -1e30f;
#pragma unroll
                for (int c = 0; c < NCT; ++c) { l[c] = p[c] * 10.0f; mx = fmaxf(mx, l[c]); }
                float ssum = 0.f;
#pragma unroll
                for (int c = 0; c < NCT; ++c) ssum += __expf(l[c] - mx);
                float lse = mx + __logf(ssum);
                int lb = labels[r];
                float ce = lse - l[lb];
                atomicAdd(&sce[lb], ce);
                atomicAdd(&scn[lb], 1.f);
                atomicAdd(&sls[lb], lastl[r]);
            }
        }
        __syncthreads();
        if (tid < NCT) {
            ce1[cb * 5 + tid] = sce[tid];
            ce2[cb * 5 + tid] = scn[tid];
            ce3[cb * 5 + tid] = sls[tid];
        }
    }
}

// K2: fused gather (r14 byte-identical): read img[i],txt[i] once (f32), diag
// dot f32, fp8-e4m3 convert (scale 16), route to (mA,mC)/(mD,mB) in the
// blocked-swizzled layout. Targeted winner-array init.
__global__ __launch_bounds__(256) void k_gather(
        const float* __restrict__ img, const float* __restrict__ txt,
        const int* __restrict__ slabel, const int* __restrict__ rnk,
        const int* __restrict__ image_ids, const int* __restrict__ text_ids,
        int* __restrict__ winI, int* __restrict__ winT,
        unsigned char* __restrict__ mA, unsigned char* __restrict__ mB,
        unsigned char* __restrict__ mC, unsigned char* __restrict__ mD,
        float* __restrict__ dA) {
    int tid = threadIdx.x;
    int kk = blockIdx.x * 256 + tid;
    if (kk < NBATCH) {
        winI[image_ids[kk]] = -1;
        winT[text_ids[kk]] = -1;
    }
    int i = blockIdx.x * 4 + (tid >> 6);     // one wave per batch row
    int g = tid & 63;                         // 8-element chunk, k = 8g..8g+7
    const float4* ip = (const float4*)(img + (size_t)i * DD) + g * 2;
    const float4* tp = (const float4*)(txt + (size_t)i * DD) + g * 2;
    float4 v0 = ip[0], v1 = ip[1], t0 = tp[0], t1 = tp[1];
    float part = v0.x * t0.x + v0.y * t0.y + v0.z * t0.z + v0.w * t0.w
               + v1.x * t1.x + v1.y * t1.y + v1.z * t1.z + v1.w * t1.w;
    for (int off = 32; off; off >>= 1) part += __shfl_xor(part, off);

    int lab = (slabel[i] == 1);
    int r = rnk[i];

    int ilo = __builtin_amdgcn_cvt_pk_fp8_f32(v0.x * FPSCALE, v0.y * FPSCALE, 0, 0);
    ilo = __builtin_amdgcn_cvt_pk_fp8_f32(v0.z * FPSCALE, v0.w * FPSCALE, ilo, 1);
    int ihi = __builtin_amdgcn_cvt_pk_fp8_f32(v1.x * FPSCALE, v1.y * FPSCALE, 0, 0);
    ihi = __builtin_amdgcn_cvt_pk_fp8_f32(v1.z * FPSCALE, v1.w * FPSCALE, ihi, 1);
    int tlo = __builtin_amdgcn_cvt_pk_fp8_f32(t0.x * FPSCALE, t0.y * FPSCALE, 0, 0);
    tlo = __builtin_amdgcn_cvt_pk_fp8_f32(t0.z * FPSCALE, t0.w * FPSCALE, tlo, 1);
    int thi = __builtin_amdgcn_cvt_pk_fp8_f32(t1.x * FPSCALE, t1.y * FPSCALE, 0, 0);
    thi = __builtin_amdgcn_cvt_pk_fp8_f32(t1.z * FPSCALE, t1.w * FPSCALE, thi, 1);

    int rl = r & 127;
    int cp = g & 7;                           // chunk within K64 tile
    int gran = cp & 3, half = cp >> 2;
    int swb = ((gran * 16) ^ ((rl & 6) << 3)) + half * 8;
    size_t off = (size_t)(r >> 7) * 65536 + (size_t)(g >> 3) * 8192 + rl * 64 + swb;
    unsigned char* dI = lab ? mA : mD;        // img -> A (pos) or D (neg)
    unsigned char* dT = lab ? mC : mB;        // txt -> C (pos) or B (neg)
    *(int2*)(dI + off) = make_int2(ilo, ihi);
    *(int2*)(dT + off) = make_int2(tlo, thi);
    if (lab && g == 0) dA[r] = part;
}

__device__ __forceinline__ void gl16(const void* src, void* lds) {
    __builtin_amdgcn_global_load_lds((const __attribute__((address_space(1))) void*)src,
                                     (__attribute__((address_space(3))) void*)lds, 16, 0, 0);
}

#define VM4()  asm volatile("s_waitcnt vmcnt(4)" ::: "memory")
#define VM0()  asm volatile("s_waitcnt vmcnt(0)" ::: "memory")
#define BARR() asm volatile("s_barrier" ::: "memory")

// K3: 128x128x(K=512) fp8-e4m3 MFMA GEMM — r13 loop (control) + the 8MB
// s_I/s_T->out copy slice riding on its 94%-idle HBM (done BEFORE the
// early-exit so all 8192 blocks contribute; 128 elems/block x 2 arrays).
__global__ __launch_bounds__(256) void k_gemm(
        const unsigned char* __restrict__ mA, const unsigned char* __restrict__ mB,
        const unsigned char* __restrict__ mC, const unsigned char* __restrict__ mD,
        const float* __restrict__ dA, const int* __restrict__ cnts,
        float* __restrict__ rA0, float* __restrict__ rB0,
        float* __restrict__ rA1, float* __restrict__ rB1,
        const float* __restrict__ sI, const float* __restrict__ sT,
        float* __restrict__ out) {
    int tid = threadIdx.x;
    {   // init-copy slice: flat block id in [0,8192), 128 elems per array
        int flat = blockIdx.x + (blockIdx.y << 6) + (blockIdx.z << 12);
        if (tid < 128) {
            int iv = flat * 128 + tid;
            if (iv < NIDS) {
                out[1 + iv] = sI[iv];
                out[1 + NIDS + iv] = sT[iv];
            }
        }
    }
    int P = cnts[0], Nn = cnts[1];
    int bm = blockIdx.x * 128, bn = blockIdx.y * 128;
    if (bm >= P || bn >= Nn) return;
    int z = blockIdx.z;
    const unsigned char* Ap = (z ? mC : mA) + (size_t)blockIdx.x * 65536;
    const unsigned char* Bp = (z ? mD : mB) + (size_t)blockIdx.y * 65536;
    float* rA = z ? rA1 : rA0;
    float* rB = z ? rB1 : rB0;

    __shared__ __align__(16) char SRAW[36864];   // 32KB staging / 36KB epilogue
    char* S = SRAW;                              // buf p: A at p*16384, B at +8192

    int lane = tid & 63;
    int wid = tid >> 6;
    int wr = wid >> 1, wc = wid & 1;          // wave tile 64x64
    int bo = tid * 16;                         // staging byte offset (linear)

    int kswz = ((lane >> 4) * 16) ^ ((lane & 6) << 3);
    int abyte = (wr * 64 + (lane & 15)) * 64 + kswz;   // A frag m: +m*1024
    int bbyte = (wc * 64 + (lane & 15)) * 64 + kswz;   // B frag n: +n*1024

    f32x4 acc[4][4];
#pragma unroll
    for (int m = 0; m < 4; ++m)
#pragma unroll
        for (int n = 0; n < 4; ++n) acc[m][n] = (f32x4){0.f, 0.f, 0.f, 0.f};

#define STAGE(kt, p) do { \
        gl16(Ap + (kt) * 8192 + bo,        S + (p) * 16384 + bo); \
        gl16(Ap + (kt) * 8192 + bo + 4096, S + (p) * 16384 + bo + 4096); \
        gl16(Bp + (kt) * 8192 + bo,        S + (p) * 16384 + 8192 + bo); \
        gl16(Bp + (kt) * 8192 + bo + 4096, S + (p) * 16384 + 8192 + bo + 4096); } while (0)

    STAGE(0, 0);
    STAGE(1, 1);
    VM4();                 // own tile-0 loads landed (tile-1's 4 still in flight)
    BARR();                // publish tile 0

#pragma unroll
    for (int kt = 0; kt < 8; ++kt) {
        const int cur = kt & 1;
        const char* base = S + cur * 16384;
        lx2 af[4], bf[4];
#pragma unroll
        for (int m = 0; m < 4; ++m)
            af[m] = *(const lx2*)(base + abyte + m * 1024);
#pragma unroll
        for (int n = 0; n < 4; ++n)
            bf[n] = *(const lx2*)(base + 8192 + bbyte + n * 1024);
#pragma unroll
        for (int m = 0; m < 4; ++m)
#pragma unroll
            for (int n = 0; n < 4; ++n)
                acc[m][n] = __builtin_amdgcn_mfma_f32_16x16x32_fp8_fp8(af[m][0], bf[n][0], acc[m][n], 0, 0, 0);
#pragma unroll
        for (int m = 0; m < 4; ++m)
#pragma unroll
            for (int n = 0; n < 4; ++n)
                acc[m][n] = __builtin_amdgcn_mfma_f32_16x16x32_fp8_fp8(af[m][1], bf[n][1], acc[m][n], 0, 0, 0);
        if (kt < 7) {
            BARR();                            // all waves consumed S[cur]
            if (kt + 2 < 8) {
                STAGE(kt + 2, cur);            // refill cur with tile kt+2
                VM4();                         // tile kt+1 landed (own loads)
            } else {
                VM0();                         // tail
            }
            BARR();                            // publish tile kt+1
        }
    }
#undef STAGE

    // ---- epilogue: e = exp((s-diag)/T); row-sums of e and e*df via LDS ----
    BARR();                                    // all waves done with staging LDS
    float* F = (float*)SRAW;                   // row R = wc*128+wr*64+wrow, stride 36, 16x(pa,pb)
    int col = lane & 15;
    int rsub = (lane >> 4) * 4;
    int rowbase = bm + wr * 64;
    int colb = bn + wc * 64 + col;
    int fb = ((wc << 7) + (wr << 6)) * 36 + col * 2;
#pragma unroll
    for (int m = 0; m < 4; ++m) {
#pragma unroll
        for (int r = 0; r < 4; ++r) {
            int wrow = m * 16 + rsub + r;
            float dv = dA[rowbase + wrow];
            float pa = 0.f, pb = 0.f;
#pragma unroll
            for (int n = 0; n < 4; ++n) {
                int gcol = colb + n * 16;
                float sv = acc[m][n][r] * INV_SIMSCALE;
                float df = sv - dv;
                float e = (gcol < Nn) ? __expf(df * INV_TEMP) : 0.f;
                pa += e;
                pb += e * df;
            }
            *(float2*)&F[fb + wrow * 36] = make_float2(pa, pb);
        }
    }
    BARR();
    {
        int row = tid >> 1;
        int half = tid & 1;
        const float4* Fr = (const float4*)&F[((half << 7) + row) * 36];
        float sa = 0.f, sb = 0.f;
#pragma unroll
        for (int q = 0; q < 8; ++q) {
            float4 v = Fr[q];
            sa += v.x + v.z;
            sb += v.y + v.w;
        }
        sa += __shfl_xor(sa, 1);
        sb += __shfl_xor(sb, 1);
        int grow = bm + row;
        if (!half && grow < P) {
            atomicAdd(&rA[grow], sa);
            atomicAdd(&rB[grow], sb);
        }
    }
}

// K4: per-positive finalize: g, s-update, per-row losses (per-wave partial
// stores), winner atomicMax
__global__ void k_posfin(const int* __restrict__ cnts, const int* __restrict__ pos,
                         const float* __restrict__ rA0, const float* __restrict__ rB0,
                         const float* __restrict__ rA1, const float* __restrict__ rB1,
                         const int* __restrict__ image_ids, const int* __restrict__ text_ids,
                         const float* __restrict__ sIin, const float* __restrict__ sTin,
                         const int* __restrict__ epochp,
                         float* __restrict__ sIv, float* __restrict__ sTv,
                         int* __restrict__ winI, int* __restrict__ winT,
                         float* __restrict__ lp) {
    int k = blockIdx.x * 256 + threadIdx.x;
    int P = cnts[0], Nn = cnts[1];
    float invNn = 1.f / (float)Nn;
    int epoch = epochp[0];
    float lI = 0.f, lT = 0.f;
    if (k < P) {
        int i = pos[k];
        int idI = image_ids[i], idT = text_ids[i];
        float gI = rA0[k] * invNn;
        float sIvk = (epoch == 0) ? gI : 0.2f * sIin[idI] + 0.8f * gI;
        lI = (rB0[k] * invNn) / (sIvk + EPSF);
        float gT = rA1[k] * invNn;
        float sTvk = (epoch == 0) ? gT : 0.2f * sTin[idT] + 0.8f * gT;
        lT = (rB1[k] * invNn) / (sTvk + EPSF);
        sIv[k] = sIvk;
        sTv[k] = sTvk;
        atomicMax(&winI[idI], k);
        atomicMax(&winT[idT], k);
    }
    for (int off = 32; off; off >>= 1) { lI += __shfl_xor(lI, off); lT += __shfl_xor(lT, off); }
    if ((threadIdx.x & 63) == 0) {
        int slot = blockIdx.x * 4 + (threadIdx.x >> 6);
        lp[slot * 2] = lI;
        lp[slot * 2 + 1] = lT;
    }
}

// K5: scatter (last-occurrence-wins) + partial reductions + final scalars
__global__ void k_fin(const int* __restrict__ cnts, const int* __restrict__ pos,
                      const int* __restrict__ image_ids, const int* __restrict__ text_ids,
                      const int* __restrict__ winI, const int* __restrict__ winT,
                      const float* __restrict__ sIv, const float* __restrict__ sTv,
                      const float* __restrict__ lp, const float* __restrict__ ce1,
                      const float* __restrict__ ce2, const float* __restrict__ ce3,
                      const float* __restrict__ u, float* __restrict__ out) {
    int P = cnts[0];
    int k = blockIdx.x * 256 + threadIdx.x;
    if (k < P) {
        int i = pos[k];
        int a = image_ids[i];
        if (winI[a] == k) out[1 + a] = sIv[k];
        int b = text_ids[i];
        if (winT[b] == k) out[1 + NIDS + b] = sTv[k];
    }
    if (blockIdx.x == 0 && threadIdx.x < 64) {
        int lane = threadIdx.x;
        float lI = lp[2 * lane] + lp[2 * (lane + 64)];
        float lT = lp[2 * lane + 1] + lp[2 * (lane + 64) + 1];
        for (int off = 32; off; off >>= 1) { lI += __shfl_xor(lI, off); lT += __shfl_xor(lT, off); }
        float ce[NCT], cn[NCT], ls[NCT];
#pragma unroll
        for (int c = 0; c < NCT; ++c) {
            float a1 = ce1[lane * 5 + c], a2 = ce2[lane * 5 + c], a3 = ce3[lane * 5 + c];
            for (int off = 32; off; off >>= 1) {
                a1 += __shfl_xor(a1, off);
                a2 += __shfl_xor(a2, off);
                a3 += __shfl_xor(a3, off);
            }
            ce[c] = a1; cn[c] = a2; ls[c] = a3;
        }
        if (lane == 0) {
            float Pf = (float)P;
            float contrast = lI / Pf + lT / Pf;
            float u_sum = 0.f;
            float mc[NCT], cv[NCT], u_new[NCT];
            bool pres[NCT];
#pragma unroll
            for (int c = 0; c < NCT; ++c) {
                pres[c] = cn[c] > 0.f;
                float safe = fmaxf(cn[c], 1.f);
                mc[c] = ce[c] / safe;
                float ml = ls[c] / safe;
                cv[c] = mc[c] - ml;
                if (pres[c]) u_sum += u[c];
            }
            float np_ = 0.f, csum = 0.f;
#pragma unroll
            for (int c = 0; c < NCT; ++c) {
                float uu = (u_sum == 0.f) ? cv[c] : 0.2f * u[c] + 0.8f * cv[c];
                u_new[c] = pres[c] ? uu : u[c];
                if (pres[c]) {
                    np_ += 1.f;
                    csum += fmaxf(40.0f * u_new[c], 0.f) * mc[c] * 0.1f;
                }
                out[1 + 2 * NIDS + c] = u_new[c];
            }
            out[0] = contrast + csum / np_;
        }
    }
}

extern "C" void kernel_launch(void* const* d_in, const int* in_sizes, int n_in,
                              void* d_out, int out_size, void* d_ws, size_t ws_size,
                              hipStream_t stream) {
    const float* img = (const float*)d_in[0];
    const float* txt = (const float*)d_in[1];
    const int* image_ids = (const int*)d_in[2];
    const int* text_ids = (const int*)d_in[3];
    const int* slabel = (const int*)d_in[4];
    const int* epoch = (const int*)d_in[5];
    const float* imgc = (const float*)d_in[6];
    const float* tfc = (const float*)d_in[7];
    const int* labels = (const int*)d_in[8];
    const float* lastl = (const float*)d_in[9];
    const float* sI = (const float*)d_in[10];
    const float* sT = (const float*)d_in[11];
    const float* u = (const float*)d_in[12];
    float* out = (float*)d_out;
    char* ws = (char*)d_ws;

    float* lp = (float*)(ws + OFF_LP);
    float* ce1 = (float*)(ws + OFF_CE1);
    float* ce2 = (float*)(ws + OFF_CE2);
    float* ce3 = (float*)(ws + OFF_CE3);
    int* pos = (int*)(ws + OFF_POS);
    int* rnk = (int*)(ws + OFF_RNK);
    int* cnts = (int*)(ws + OFF_CNT);
    float* dA = (float*)(ws + OFF_DA);
    float* rA0 = (float*)(ws + OFF_RA0);
    float* rB0 = (float*)(ws + OFF_RB0);
    float* rA1 = (float*)(ws + OFF_RA1);
    float* rB1 = (float*)(ws + OFF_RB1);
    float* sIv = (float*)(ws + OFF_SIV);
    float* sTv = (float*)(ws + OFF_STV);
    int* winI = (int*)(ws + OFF_WINI);
    int* winT = (int*)(ws + OFF_WINT);
    unsigned char* mA = (unsigned char*)(ws + OFF_MA);
    unsigned char* mB = (unsigned char*)(ws + OFF_MB);
    unsigned char* mC = (unsigned char*)(ws + OFF_MC);
    unsigned char* mD = (unsigned char*)(ws + OFF_MD);

    k_pre<<<65, 256, 0, stream>>>(rA0, rB0, rA1, rB1, slabel, pos, rnk, cnts,
                                  imgc, tfc, labels, lastl, ce1, ce2, ce3);
    k_gather<<<2048, 256, 0, stream>>>(img, txt, slabel, rnk, image_ids, text_ids,
                                       winI, winT, mA, mB, mC, mD, dA);
    k_gemm<<<dim3(64, 64, 2), 256, 0, stream>>>(mA, mB, mC, mD, dA, cnts,
                                                rA0, rB0, rA1, rB1, sI, sT, out);
    k_posfin<<<32, 256, 0, stream>>>(cnts, pos, rA0, rB0, rA1, rB1, image_ids, text_ids,
                                     sI, sT, epoch, sIv, sTv, winI, winT, lp);
    k_fin<<<32, 256, 0, stream>>>(cnts, pos, image_ids, text_ids, winI, winT,
                                  sIv, sTv, lp, ce1, ce2, ce3, u, out);
}

// Round 17
// 75.982 us; speedup vs baseline: 1.1136x; 1.0276x over previous
//
#include <hip/hip_runtime.h>

#define NBATCH 8192
#define DD 512
#define NIDS 1000000
#define BCNT 4096
#define NCT 5
#define INV_TEMP 14.285714285714286f
#define EPSF 1.1920929e-07f
#define FPSCALE 16.0f
#define INV_SIMSCALE (1.0f / 256.0f)

typedef __attribute__((ext_vector_type(4))) float f32x4;
typedef __attribute__((ext_vector_type(2))) long lx2;

// ---------------- workspace layout (bytes) ----------------
#define OFF_LP     ((size_t)0)            // 256 floats: 32 blk x 4 wave x (lI,lT)
#define OFF_CE1    ((size_t)1024)         // 320 floats: CE sum partials
#define OFF_CE2    ((size_t)2304)         // 320 floats: count partials
#define OFF_CE3    ((size_t)3584)         // 320 floats: last-loss partials
#define OFF_POS    ((size_t)(32*1024))
#define OFF_RNK    ((size_t)(64*1024))
#define OFF_CNT    ((size_t)(96*1024))
#define OFF_DA     ((size_t)(100*1024))
#define OFF_RA0    ((size_t)(132*1024))
#define OFF_RB0    ((size_t)(164*1024))
#define OFF_RA1    ((size_t)(196*1024))
#define OFF_RB1    ((size_t)(228*1024))
#define OFF_SIV    ((size_t)(260*1024))
#define OFF_STV    ((size_t)(292*1024))
#define OFF_WINI   ((size_t)(324*1024))
#define OFF_WINT   (OFF_WINI + 4000000)
#define OFF_MA     (OFF_WINT + 4000000)
#define MATB       ((size_t)(8192*512*2))
#define OFF_MB     (OFF_MA + MATB)
#define OFF_MC     (OFF_MB + MATB)
#define OFF_MD     (OFF_MC + MATB)

// fp8 blocked-swizzled operand layout (r13-verified):
// panel = row/128 (stride 65536 B), K64-tile kc = k/64 (stride 8192 B),
// within-tile row-major [128][64B]; each 64B row = 4 granules of 16B;
// granule c holds k-bytes [8c..8c+7] ++ [32+8c..32+8c+7]; granule base byte
// XOR-swizzled by ((row&6)<<3) — verified-0-conflict algebra.

// K1 (fused front-end): bid 0..63 = CE, bid 64 = compaction, all 3972
// blocks also do their init slice (s copy, rA/rB zero).
__global__ __launch_bounds__(256) void k_pre(
        const float* __restrict__ sI, const float* __restrict__ sT,
        float* __restrict__ out,
        float* __restrict__ rA0, float* __restrict__ rB0,
        float* __restrict__ rA1, float* __restrict__ rB1,
        const int* __restrict__ slabel, int* __restrict__ pos,
        int* __restrict__ rnk, int* __restrict__ cnts,
        const float* __restrict__ imgc, const float* __restrict__ tfc,
        const int* __restrict__ labels, const float* __restrict__ lastl,
        float* __restrict__ ce1, float* __restrict__ ce2, float* __restrict__ ce3) {
    int bid = blockIdx.x;
    int tid = threadIdx.x;
    // ---- init slice (s copy, row-accumulator zero) ----
    int iv = bid * 256 + tid;
    if (iv < NIDS) {
        out[1 + iv] = sI[iv];
        out[1 + NIDS + iv] = sT[iv];
    }
    if (iv < NBATCH) { rA0[iv] = 0.f; rB0[iv] = 0.f; rA1[iv] = 0.f; rB1[iv] = 0.f; }
    if (bid > 64) return;

    if (bid == 64) {
        // ---- compaction: 256 threads x 32 items, stable scan ----
        __shared__ int sums[256];
        int base = tid * 32;
        int c = 0;
        for (int j = 0; j < 32; ++j) c += (slabel[base + j] == 1);
        sums[tid] = c;
        __syncthreads();
        for (int off = 1; off < 256; off <<= 1) {
            int add = (tid >= off) ? sums[tid - off] : 0;
            __syncthreads();
            sums[tid] += add;
            __syncthreads();
        }
        int p = sums[tid] - c;   // exclusive prefix of pos count
        for (int j = 0; j < 32; ++j) {
            int idx = base + j;
            if (slabel[idx] == 1) { pos[p] = idx; rnk[idx] = p; p++; }
            else rnk[idx] = idx - p;
        }
        if (tid == 255) { cnts[0] = sums[255]; cnts[1] = NBATCH - sums[255]; }
    } else {
        // ---- CE block cb in [0,64): 4 rows/iter x 16 iters; partial outputs ----
        int cb = bid;
        __shared__ float tS[NCT * DD];
        __shared__ float sce[NCT], scn[NCT], sls[NCT];
        for (int j = tid; j < NCT * DD; j += 256) tS[j] = tfc[j];
        if (tid < NCT) { sce[tid] = 0.f; scn[tid] = 0.f; sls[tid] = 0.f; }
        __syncthreads();
        int lane = tid & 63;
        int wid = tid >> 6;
        for (int it = 0; it < 16; ++it) {
            int r = it * 256 + cb * 4 + wid;
            const float4* ip = (const float4*)(imgc + (size_t)r * DD) + lane * 2;
            float4 a0 = ip[0], a1 = ip[1];
            float p[NCT];
#pragma unroll
            for (int c = 0; c < NCT; ++c) {
                const float* t = &tS[c * DD + lane * 8];
                p[c] = a0.x * t[0] + a0.y * t[1] + a0.z * t[2] + a0.w * t[3]
                     + a1.x * t[4] + a1.y * t[5] + a1.z * t[6] + a1.w * t[7];
            }
#pragma unroll
            for (int c = 0; c < NCT; ++c)
                for (int off = 32; off; off >>= 1) p[c] += __shfl_xor(p[c], off);
            if (lane == 0) {
                float l[NCT];
                float mx = -1e30f;
#pragma unroll
                for (int c = 0; c < NCT; ++c) { l[c] = p[c] * 10.0f; mx = fmaxf(mx, l[c]); }
                float ssum = 0.f;
#pragma unroll
                for (int c = 0; c < NCT; ++c) ssum += __expf(l[c] - mx);
                float lse = mx + __logf(ssum);
                int lb = labels[r];
                float ce = lse - l[lb];
                atomicAdd(&sce[lb], ce);
                atomicAdd(&scn[lb], 1.f);
                atomicAdd(&sls[lb], lastl[r]);
            }
        }
        __syncthreads();
        if (tid < NCT) {
            ce1[cb * 5 + tid] = sce[tid];
            ce2[cb * 5 + tid] = scn[tid];
            ce3[cb * 5 + tid] = sls[tid];
        }
    }
}

// K2: fused gather: read img[i],txt[i] once (f32), diag dot in f32,
// fp8-e4m3 convert (scale 16), route to (mA,mC) pos / (mD,mB) neg in the
// fp8 blocked-swizzled layout. Targeted winner-array init.
__global__ __launch_bounds__(256) void k_gather(
        const float* __restrict__ img, const float* __restrict__ txt,
        const int* __restrict__ slabel, const int* __restrict__ rnk,
        const int* __restrict__ image_ids, const int* __restrict__ text_ids,
        int* __restrict__ winI, int* __restrict__ winT,
        unsigned char* __restrict__ mA, unsigned char* __restrict__ mB,
        unsigned char* __restrict__ mC, unsigned char* __restrict__ mD,
        float* __restrict__ dA) {
    int tid = threadIdx.x;
    int kk = blockIdx.x * 256 + tid;
    if (kk < NBATCH) {
        winI[image_ids[kk]] = -1;
        winT[text_ids[kk]] = -1;
    }
    int i = blockIdx.x * 4 + (tid >> 6);     // one wave per batch row
    int g = tid & 63;                         // 8-element chunk, k = 8g..8g+7
    const float4* ip = (const float4*)(img + (size_t)i * DD) + g * 2;
    const float4* tp = (const float4*)(txt + (size_t)i * DD) + g * 2;
    float4 v0 = ip[0], v1 = ip[1], t0 = tp[0], t1 = tp[1];
    float part = v0.x * t0.x + v0.y * t0.y + v0.z * t0.z + v0.w * t0.w
               + v1.x * t1.x + v1.y * t1.y + v1.z * t1.z + v1.w * t1.w;
    for (int off = 32; off; off >>= 1) part += __shfl_xor(part, off);

    int lab = (slabel[i] == 1);
    int r = rnk[i];

    int ilo = __builtin_amdgcn_cvt_pk_fp8_f32(v0.x * FPSCALE, v0.y * FPSCALE, 0, 0);
    ilo = __builtin_amdgcn_cvt_pk_fp8_f32(v0.z * FPSCALE, v0.w * FPSCALE, ilo, 1);
    int ihi = __builtin_amdgcn_cvt_pk_fp8_f32(v1.x * FPSCALE, v1.y * FPSCALE, 0, 0);
    ihi = __builtin_amdgcn_cvt_pk_fp8_f32(v1.z * FPSCALE, v1.w * FPSCALE, ihi, 1);
    int tlo = __builtin_amdgcn_cvt_pk_fp8_f32(t0.x * FPSCALE, t0.y * FPSCALE, 0, 0);
    tlo = __builtin_amdgcn_cvt_pk_fp8_f32(t0.z * FPSCALE, t0.w * FPSCALE, tlo, 1);
    int thi = __builtin_amdgcn_cvt_pk_fp8_f32(t1.x * FPSCALE, t1.y * FPSCALE, 0, 0);
    thi = __builtin_amdgcn_cvt_pk_fp8_f32(t1.z * FPSCALE, t1.w * FPSCALE, thi, 1);

    int rl = r & 127;
    int cp = g & 7;                           // chunk within K64 tile
    int gran = cp & 3, half = cp >> 2;
    int swb = ((gran * 16) ^ ((rl & 6) << 3)) + half * 8;
    size_t off = (size_t)(r >> 7) * 65536 + (size_t)(g >> 3) * 8192 + rl * 64 + swb;
    unsigned char* dI = lab ? mA : mD;        // img -> A (pos) or D (neg)
    unsigned char* dT = lab ? mC : mB;        // txt -> C (pos) or B (neg)
    *(int2*)(dI + off) = make_int2(ilo, ihi);
    *(int2*)(dT + off) = make_int2(tlo, thi);
    if (lab && g == 0) dA[r] = part;
}

__device__ __forceinline__ void gl16(const void* src, void* lds) {
    __builtin_amdgcn_global_load_lds((const __attribute__((address_space(1))) void*)src,
                                     (__attribute__((address_space(3))) void*)lds, 16, 0, 0);
}

#define VM4()  asm volatile("s_waitcnt vmcnt(4)" ::: "memory")
#define VM0()  asm volatile("s_waitcnt vmcnt(0)" ::: "memory")
#define BARR() asm volatile("s_barrier" ::: "memory")

// K3: 128x128x(K=512) fp8-e4m3 MFMA GEMM — r13/r14 control, byte-identical:
// 4 waves 2x2, BK=64 fp8, 2-buf, VM4 counted-vmcnt publish-barrier pipeline,
// 0-conflict swizzled ds_read_b128, 36KB LDS-staged epilogue.
// Measured at ~99% of the 128 B/cyc LDS-pipe floor (r13). No foreign VMEM
// traffic allowed in this kernel (r16 lesson: it poisons the counted vmcnt).
__global__ __launch_bounds__(256) void k_gemm(
        const unsigned char* __restrict__ mA, const unsigned char* __restrict__ mB,
        const unsigned char* __restrict__ mC, const unsigned char* __restrict__ mD,
        const float* __restrict__ dA, const int* __restrict__ cnts,
        float* __restrict__ rA0, float* __restrict__ rB0,
        float* __restrict__ rA1, float* __restrict__ rB1) {
    int P = cnts[0], Nn = cnts[1];
    int bm = blockIdx.x * 128, bn = blockIdx.y * 128;
    if (bm >= P || bn >= Nn) return;
    int z = blockIdx.z;
    const unsigned char* Ap = (z ? mC : mA) + (size_t)blockIdx.x * 65536;
    const unsigned char* Bp = (z ? mD : mB) + (size_t)blockIdx.y * 65536;
    float* rA = z ? rA1 : rA0;
    float* rB = z ? rB1 : rB0;

    __shared__ __align__(16) char SRAW[36864];   // 32KB staging / 36KB epilogue
    char* S = SRAW;                              // buf p: A at p*16384, B at +8192

    int tid = threadIdx.x;
    int lane = tid & 63;
    int wid = tid >> 6;
    int wr = wid >> 1, wc = wid & 1;          // wave tile 64x64
    int bo = tid * 16;                         // staging byte offset (linear)

    int kswz = ((lane >> 4) * 16) ^ ((lane & 6) << 3);
    int abyte = (wr * 64 + (lane & 15)) * 64 + kswz;   // A frag m: +m*1024
    int bbyte = (wc * 64 + (lane & 15)) * 64 + kswz;   // B frag n: +n*1024

    f32x4 acc[4][4];
#pragma unroll
    for (int m = 0; m < 4; ++m)
#pragma unroll
        for (int n = 0; n < 4; ++n) acc[m][n] = (f32x4){0.f, 0.f, 0.f, 0.f};

#define STAGE(kt, p) do { \
        gl16(Ap + (kt) * 8192 + bo,        S + (p) * 16384 + bo); \
        gl16(Ap + (kt) * 8192 + bo + 4096, S + (p) * 16384 + bo + 4096); \
        gl16(Bp + (kt) * 8192 + bo,        S + (p) * 16384 + 8192 + bo); \
        gl16(Bp + (kt) * 8192 + bo + 4096, S + (p) * 16384 + 8192 + bo + 4096); } while (0)

    STAGE(0, 0);
    STAGE(1, 1);
    VM4();                 // own tile-0 loads landed (tile-1's 4 still in flight)
    BARR();                // publish tile 0

#pragma unroll
    for (int kt = 0; kt < 8; ++kt) {
        const int cur = kt & 1;
        const char* base = S + cur * 16384;
        lx2 af[4], bf[4];
#pragma unroll
        for (int m = 0; m < 4; ++m)
            af[m] = *(const lx2*)(base + abyte + m * 1024);
#pragma unroll
        for (int n = 0; n < 4; ++n)
            bf[n] = *(const lx2*)(base + 8192 + bbyte + n * 1024);
#pragma unroll
        for (int m = 0; m < 4; ++m)
#pragma unroll
            for (int n = 0; n < 4; ++n)
                acc[m][n] = __builtin_amdgcn_mfma_f32_16x16x32_fp8_fp8(af[m][0], bf[n][0], acc[m][n], 0, 0, 0);
#pragma unroll
        for (int m = 0; m < 4; ++m)
#pragma unroll
            for (int n = 0; n < 4; ++n)
                acc[m][n] = __builtin_amdgcn_mfma_f32_16x16x32_fp8_fp8(af[m][1], bf[n][1], acc[m][n], 0, 0, 0);
        if (kt < 7) {
            BARR();                            // all waves consumed S[cur]
            if (kt + 2 < 8) {
                STAGE(kt + 2, cur);            // refill cur with tile kt+2
                VM4();                         // tile kt+1 landed (own loads)
            } else {
                VM0();                         // tail
            }
            BARR();                            // publish tile kt+1
        }
    }
#undef STAGE

    // ---- epilogue: e = exp((s-diag)/T); row-sums of e and e*df via LDS ----
    BARR();                                    // all waves done with staging LDS
    float* F = (float*)SRAW;                   // row R = wc*128+wr*64+wrow, stride 36, 16x(pa,pb)
    int col = lane & 15;
    int rsub = (lane >> 4) * 4;
    int rowbase = bm + wr * 64;
    int colb = bn + wc * 64 + col;
    int fb = ((wc << 7) + (wr << 6)) * 36 + col * 2;
#pragma unroll
    for (int m = 0; m < 4; ++m) {
#pragma unroll
        for (int r = 0; r < 4; ++r) {
            int wrow = m * 16 + rsub + r;
            float dv = dA[rowbase + wrow];
            float pa = 0.f, pb = 0.f;
#pragma unroll
            for (int n = 0; n < 4; ++n) {
                int gcol = colb + n * 16;
                float sv = acc[m][n][r] * INV_SIMSCALE;
                float df = sv - dv;
                float e = (gcol < Nn) ? __expf(df * INV_TEMP) : 0.f;
                pa += e;
                pb += e * df;
            }
            *(float2*)&F[fb + wrow * 36] = make_float2(pa, pb);
        }
    }
    BARR();
    {
        int row = tid >> 1;
        int half = tid & 1;
        const float4* Fr = (const float4*)&F[((half << 7) + row) * 36];
        float sa = 0.f, sb = 0.f;
#pragma unroll
        for (int q = 0; q < 8; ++q) {
            float4 v = Fr[q];
            sa += v.x + v.z;
            sb += v.y + v.w;
        }
        sa += __shfl_xor(sa, 1);
        sb += __shfl_xor(sb, 1);
        int grow = bm + row;
        if (!half && grow < P) {
            atomicAdd(&rA[grow], sa);
            atomicAdd(&rB[grow], sb);
        }
    }
}

// K4: per-positive finalize: g, s-update, per-row losses (per-wave partial
// stores), winner atomicMax
__global__ void k_posfin(const int* __restrict__ cnts, const int* __restrict__ pos,
                         const float* __restrict__ rA0, const float* __restrict__ rB0,
                         const float* __restrict__ rA1, const float* __restrict__ rB1,
                         const int* __restrict__ image_ids, const int* __restrict__ text_ids,
                         const float* __restrict__ sIin, const float* __restrict__ sTin,
                         const int* __restrict__ epochp,
                         float* __restrict__ sIv, float* __restrict__ sTv,
                         int* __restrict__ winI, int* __restrict__ winT,
                         float* __restrict__ lp) {
    int k = blockIdx.x * 256 + threadIdx.x;
    int P = cnts[0], Nn = cnts[1];
    float invNn = 1.f / (float)Nn;
    int epoch = epochp[0];
    float lI = 0.f, lT = 0.f;
    if (k < P) {
        int i = pos[k];
        int idI = image_ids[i], idT = text_ids[i];
        float gI = rA0[k] * invNn;
        float sIvk = (epoch == 0) ? gI : 0.2f * sIin[idI] + 0.8f * gI;
        lI = (rB0[k] * invNn) / (sIvk + EPSF);
        float gT = rA1[k] * invNn;
        float sTvk = (epoch == 0) ? gT : 0.2f * sTin[idT] + 0.8f * gT;
        lT = (rB1[k] * invNn) / (sTvk + EPSF);
        sIv[k] = sIvk;
        sTv[k] = sTvk;
        atomicMax(&winI[idI], k);
        atomicMax(&winT[idT], k);
    }
    for (int off = 32; off; off >>= 1) { lI += __shfl_xor(lI, off); lT += __shfl_xor(lT, off); }
    if ((threadIdx.x & 63) == 0) {
        int slot = blockIdx.x * 4 + (threadIdx.x >> 6);
        lp[slot * 2] = lI;
        lp[slot * 2 + 1] = lT;
    }
}

// K5: scatter (last-occurrence-wins) + partial reductions + final scalars
__global__ void k_fin(const int* __restrict__ cnts, const int* __restrict__ pos,
                      const int* __restrict__ image_ids, const int* __restrict__ text_ids,
                      const int* __restrict__ winI, const int* __restrict__ winT,
                      const float* __restrict__ sIv, const float* __restrict__ sTv,
                      const float* __restrict__ lp, const float* __restrict__ ce1,
                      const float* __restrict__ ce2, const float* __restrict__ ce3,
                      const float* __restrict__ u, float* __restrict__ out) {
    int P = cnts[0];
    int k = blockIdx.x * 256 + threadIdx.x;
    if (k < P) {
        int i = pos[k];
        int a = image_ids[i];
        if (winI[a] == k) out[1 + a] = sIv[k];
        int b = text_ids[i];
        if (winT[b] == k) out[1 + NIDS + b] = sTv[k];
    }
    if (blockIdx.x == 0 && threadIdx.x < 64) {
        int lane = threadIdx.x;
        float lI = lp[2 * lane] + lp[2 * (lane + 64)];
        float lT = lp[2 * lane + 1] + lp[2 * (lane + 64) + 1];
        for (int off = 32; off; off >>= 1) { lI += __shfl_xor(lI, off); lT += __shfl_xor(lT, off); }
        float ce[NCT], cn[NCT], ls[NCT];
#pragma unroll
        for (int c = 0; c < NCT; ++c) {
            float a1 = ce1[lane * 5 + c], a2 = ce2[lane * 5 + c], a3 = ce3[lane * 5 + c];
            for (int off = 32; off; off >>= 1) {
                a1 += __shfl_xor(a1, off);
                a2 += __shfl_xor(a2, off);
                a3 += __shfl_xor(a3, off);
            }
            ce[c] = a1; cn[c] = a2; ls[c] = a3;
        }
        if (lane == 0) {
            float Pf = (float)P;
            float contrast = lI / Pf + lT / Pf;
            float u_sum = 0.f;
            float mc[NCT], cv[NCT], u_new[NCT];
            bool pres[NCT];
#pragma unroll
            for (int c = 0; c < NCT; ++c) {
                pres[c] = cn[c] > 0.f;
                float safe = fmaxf(cn[c], 1.f);
                mc[c] = ce[c] / safe;
                float ml = ls[c] / safe;
                cv[c] = mc[c] - ml;
                if (pres[c]) u_sum += u[c];
            }
            float np_ = 0.f, csum = 0.f;
#pragma unroll
            for (int c = 0; c < NCT; ++c) {
                float uu = (u_sum == 0.f) ? cv[c] : 0.2f * u[c] + 0.8f * cv[c];
                u_new[c] = pres[c] ? uu : u[c];
                if (pres[c]) {
                    np_ += 1.f;
                    csum += fmaxf(40.0f * u_new[c], 0.f) * mc[c] * 0.1f;
                }
                out[1 + 2 * NIDS + c] = u_new[c];
            }
            out[0] = contrast + csum / np_;
        }
    }
}

extern "C" void kernel_launch(void* const* d_in, const int* in_sizes, int n_in,
                              void* d_out, int out_size, void* d_ws, size_t ws_size,
                              hipStream_t stream) {
    const float* img = (const float*)d_in[0];
    const float* txt = (const float*)d_in[1];
    const int* image_ids = (const int*)d_in[2];
    const int* text_ids = (const int*)d_in[3];
    const int* slabel = (const int*)d_in[4];
    const int* epoch = (const int*)d_in[5];
    const float* imgc = (const float*)d_in[6];
    const float* tfc = (const float*)d_in[7];
    const int* labels = (const int*)d_in[8];
    const float* lastl = (const float*)d_in[9];
    const float* sI = (const float*)d_in[10];
    const float* sT = (const float*)d_in[11];
    const float* u = (const float*)d_in[12];
    float* out = (float*)d_out;
    char* ws = (char*)d_ws;

    float* lp = (float*)(ws + OFF_LP);
    float* ce1 = (float*)(ws + OFF_CE1);
    float* ce2 = (float*)(ws + OFF_CE2);
    float* ce3 = (float*)(ws + OFF_CE3);
    int* pos = (int*)(ws + OFF_POS);
    int* rnk = (int*)(ws + OFF_RNK);
    int* cnts = (int*)(ws + OFF_CNT);
    float* dA = (float*)(ws + OFF_DA);
    float* rA0 = (float*)(ws + OFF_RA0);
    float* rB0 = (float*)(ws + OFF_RB0);
    float* rA1 = (float*)(ws + OFF_RA1);
    float* rB1 = (float*)(ws + OFF_RB1);
    float* sIv = (float*)(ws + OFF_SIV);
    float* sTv = (float*)(ws + OFF_STV);
    int* winI = (int*)(ws + OFF_WINI);
    int* winT = (int*)(ws + OFF_WINT);
    unsigned char* mA = (unsigned char*)(ws + OFF_MA);
    unsigned char* mB = (unsigned char*)(ws + OFF_MB);
    unsigned char* mC = (unsigned char*)(ws + OFF_MC);
    unsigned char* mD = (unsigned char*)(ws + OFF_MD);

    k_pre<<<3972, 256, 0, stream>>>(sI, sT, out, rA0, rB0, rA1, rB1,
                                    slabel, pos, rnk, cnts,
                                    imgc, tfc, labels, lastl, ce1, ce2, ce3);
    k_gather<<<2048, 256, 0, stream>>>(img, txt, slabel, rnk, image_ids, text_ids,
                                       winI, winT, mA, mB, mC, mD, dA);
    k_gemm<<<dim3(64, 64, 2), 256, 0, stream>>>(mA, mB, mC, mD, dA, cnts, rA0, rB0, rA1, rB1);
    k_posfin<<<32, 256, 0, stream>>>(cnts, pos, rA0, rB0, rA1, rB1, image_ids, text_ids,
                                     sI, sT, epoch, sIv, sTv, winI, winT, lp);
    k_fin<<<32, 256, 0, stream>>>(cnts, pos, image_ids, text_ids, winI, winT,
                                  sIv, sTv, lp, ce1, ce2, ce3, u, out);
}